// Round 9
// baseline (152.746 us; speedup 1.0000x reference)
//
#include <hip/hip_runtime.h>

static constexpr int C    = 64;
static constexpr int H    = 128;
static constexpr int W    = 128;
static constexpr int NPIX = H * W;      // 16384
static constexpr int PAD  = 3;          // WS=7 -> +-3

typedef float vf4 __attribute__((ext_vector_type(4)));   // NT-store-able

// ---------------------------------------------------------------------------
// 1) conv1x1, z-merged + NT stores + ROTATED channel-load order.
//    All blocks previously issued x[c*NPIX+p] with c = 0,1,2,... in lockstep:
//    at any instant the whole GPU read ONE 64KB row of x -> few DRAM channels
//    -> ~1 TB/s effective (explains the stubborn ~21 us). rot = (bx&15)*4
//    staggers blocks across 16 rows (1 MB instantaneous footprint).
//    xr[] stays statically indexed (slot cc holds channel (cc+rot)&63);
//    the W index is rotated identically (wave-uniform -> still s_load).
// ---------------------------------------------------------------------------
__global__ __launch_bounds__(256, 4) void k_conv(
    const float* __restrict__ x,
    const float* __restrict__ Wq, const float* __restrict__ bq,
    const float* __restrict__ Wk, const float* __restrict__ bk,
    const float* __restrict__ Wv, const float* __restrict__ bv,
    float* __restrict__ qT, float* __restrict__ ko, float* __restrict__ vo)
{
    const int tid  = threadIdx.x;
    const int lane = tid & 63;
    const int p    = blockIdx.x * 64 + lane;
    const int o0   = __builtin_amdgcn_readfirstlane(
                         blockIdx.y * 16 + (tid >> 6) * 4);
    const int rot  = __builtin_amdgcn_readfirstlane((blockIdx.x & 15) << 2);

    float xr[C];                         // slot cc <-> channel (cc+rot)&63
#pragma unroll
    for (int cc = 0; cc < C; ++cc) {
        const int ch = (cc + rot) & 63;
        xr[cc] = x[ch * NPIX + p];
    }

    float aq[4], ak[4], av[4];
#pragma unroll
    for (int j = 0; j < 4; ++j) {
        aq[j] = bq[o0 + j];
        ak[j] = bk[o0 + j];
        av[j] = bv[o0 + j];
    }

#pragma unroll
    for (int cc = 0; cc < C; ++cc) {
        const int ch = (cc + rot) & 63;  // wave-uniform
        const float xv = xr[cc];
#pragma unroll
        for (int j = 0; j < 4; ++j) {
            aq[j] += Wq[(o0 + j) * C + ch] * xv;
            ak[j] += Wk[(o0 + j) * C + ch] * xv;
            av[j] += Wv[(o0 + j) * C + ch] * xv;
        }
    }

    vf4 qv4 = { aq[0], aq[1], aq[2], aq[3] };
    __builtin_nontemporal_store(qv4, (vf4*)(qT + (size_t)p * C + o0));
#pragma unroll
    for (int j = 0; j < 4; ++j) {
        __builtin_nontemporal_store(ak[j], ko + (size_t)(o0 + j) * NPIX + p);
        __builtin_nontemporal_store(av[j], vo + (size_t)(o0 + j) * NPIX + p);
    }
}

// ---------------------------------------------------------------------------
// 2) merged dispatch: [gram+diag] (blocks 0..1023) and [7x7 box of v]
//    (blocks 1024..1535). Gram k-loads get the same rotated-order fix
//    (kmat[c*NPIX+...] is the identical 64KB-stride lockstep pattern).
//    ks0/ks1 slots static; q LDS-broadcast index rotated to match
//    (rot multiple of 4 keeps float4 alignment). Rest round-6 exact.
// ---------------------------------------------------------------------------
__global__ __launch_bounds__(256, 3) void k_mid(
    const float* __restrict__ qT, const float* __restrict__ kmat,
    const float* __restrict__ v,
    float* __restrict__ Sd, float* __restrict__ Vs)
{
    __shared__ union {
        struct { float Sl[22][130]; float qs[22][64]; } g;   // 16.7 KB
        struct { float vt[22][128]; float vh[22][128]; } box; // 22.5 KB
    } u;
    const int bid = blockIdx.x;
    const int tid = threadIdx.x;

    if (bid < 1024) {
        // ----- fused row-Gram + diagonal 7-sum -----
        const int h   = bid >> 3;
        const int w0  = (bid & 7) * 16;

        // stage q rows w0-3 .. w0+18 (zero-filled outside [0,W))
        for (int i = tid; i < 22 * 16; i += 256) {
            int r  = i >> 4, c4 = (i & 15) << 2;
            int wp = w0 - 3 + r;
            float4 qv = make_float4(0.f, 0.f, 0.f, 0.f);
            if (wp >= 0 && wp < W)
                qv = *(const float4*)(qT + (size_t)(h * W + wp) * C + c4);
            *(float4*)(&u.g.qs[r][c4]) = qv;
        }

        // two k-columns per thread, ROTATED load order
        const int kkt = tid & 63;
        const int g   = tid >> 6;            // 0..3, wave-uniform row group
        const int rot = __builtin_amdgcn_readfirstlane((bid & 15) << 2);
        float ks0[C], ks1[C];                // slot cc <-> channel (cc+rot)&63
#pragma unroll
        for (int cc = 0; cc < C; ++cc) {
            const int ch = (cc + rot) & 63;
            ks0[cc] = kmat[ch * NPIX + h * W + kkt];
            ks1[cc] = kmat[ch * NPIX + h * W + kkt + 64];
        }
        __syncthreads();

        for (int j = 0; j < 6; ++j) {
            int row = g * 6 + j;             // 0..23, wave-uniform
            if (row < 22) {                  // wave-uniform branch
                float a0 = 0.f, a1 = 0.f, a2 = 0.f, a3 = 0.f;
                float b0 = 0.f, b1 = 0.f, b2 = 0.f, b3 = 0.f;
#pragma unroll
                for (int cc = 0; cc < C; cc += 4) {
                    const int ch = (cc + rot) & 63;          // 4-aligned
                    float4 qv = *(const float4*)(&u.g.qs[row][ch]); // broadcast
                    a0 += qv.x * ks0[cc + 0];  b0 += qv.x * ks1[cc + 0];
                    a1 += qv.y * ks0[cc + 1];  b1 += qv.y * ks1[cc + 1];
                    a2 += qv.z * ks0[cc + 2];  b2 += qv.z * ks1[cc + 2];
                    a3 += qv.w * ks0[cc + 3];  b3 += qv.w * ks1[cc + 3];
                }
                u.g.Sl[row][kkt]      = (a0 + a1) + (a2 + a3);
                u.g.Sl[row][kkt + 64] = (b0 + b1) + (b2 + b3);
            }
        }
        __syncthreads();

        // ----- diagonal 7-sum (unchanged) -----
        const int kk  = tid & 127;
        const int wsl = tid >> 7;            // 0/1, wave-uniform
#pragma unroll
        for (int r = 0; r < 8; ++r) {
            int wl = wsl * 8 + r;            // 0..15
            float a = 0.f;
#pragma unroll
            for (int dd = -PAD; dd <= PAD; ++dd) {
                int kj = kk + dd;
                if (kj >= 0 && kj < W)
                    a += u.g.Sl[wl + 3 + dd][kj];
            }
            Sd[(size_t)(h * W + w0 + wl) * W + kk] = a;
        }
    } else {
        // ----- 7x7 box sum of v (separable in LDS, unchanged) -----
        const int b2 = bid - 1024;           // 0..511
        const int c  = b2 >> 3;              // 0..63
        const int h0 = (b2 & 7) * 16;

        for (int i = tid; i < 22 * 128; i += 256) {
            int r = i >> 7, w = i & 127;
            int h = h0 - 3 + r;
            u.box.vt[r][w] = (h >= 0 && h < H) ? v[c * NPIX + h * W + w] : 0.f;
        }
        __syncthreads();
        for (int i = tid; i < 22 * 128; i += 256) {
            int r = i >> 7, w = i & 127;
            float s = 0.f;
#pragma unroll
            for (int d = -PAD; d <= PAD; ++d) {
                int wj = w + d;
                if (wj >= 0 && wj < W) s += u.box.vt[r][wj];
            }
            u.box.vh[r][w] = s;
        }
        __syncthreads();
        for (int i = tid; i < 16 * 128; i += 256) {
            int r = i >> 7, w = i & 127;
            float s = 0.f;
#pragma unroll
            for (int d = 0; d < 7; ++d) s += u.box.vh[r + d][w];
            Vs[c * NPIX + (h0 + r) * W + w] = s;
        }
    }
}

// ---------------------------------------------------------------------------
// 3) FUSED vertical-7-sum + softmax + PV, 1024-thread version.  [r5 exact]
//    grid (H, 2) = 256 blocks x 1024 thr; 32 waves/CU. One barrier.
//    (Sd reads are 32KB-contiguous per block per instant and blocks are
//    spread over h -> no channel-conflict issue here.)
// ---------------------------------------------------------------------------
__global__ __launch_bounds__(1024, 4) void k_fused(
    const float* __restrict__ Sd, const float* __restrict__ Vs,
    float* __restrict__ out)
{
    constexpr int AP = 129;          // attn LDS pitch
    __shared__ float At[64][AP];     // attn[w-local][kk], 33.0 KB
    __shared__ float Vl[64][128];    // Vs[c][kk],         32.8 KB

    const int h   = blockIdx.x;
    const int w0  = blockIdx.y * 64;
    const int tid = threadIdx.x;

    // ---- issue Vs staging loads early (consumed after phase A) ----
    float4 vstage[2];
#pragma unroll
    for (int r = 0; r < 2; ++r) {
        int L  = tid + r * 1024;         // 0..2047 float4 tiles
        int c  = L >> 5;                 // 32 float4 per channel row
        int k4 = (L & 31) << 2;
        vstage[r] = *(const float4*)(Vs + (size_t)c * NPIX + h * W + k4);
    }

    // ---- phase A: logits (vertical 7-sum of Sd) + softmax into LDS ----
    const int wl = tid >> 4;             // 0..63 (w within half)
    const int s  = tid & 15;             // kk-16th: kk = s*8 + e

    float4 g0 = make_float4(0.f, 0.f, 0.f, 0.f);
    float4 g1 = g0;
#pragma unroll
    for (int i = 0; i < 7; ++i) {
        int hp = h - 3 + i;              // block-uniform branch
        if (hp >= 0 && hp < H) {
            const float4* src = (const float4*)(
                Sd + (size_t)hp * NPIX + (w0 + wl) * W + s * 8);
            float4 a = src[0], b = src[1];
            g0.x += a.x; g0.y += a.y; g0.z += a.z; g0.w += a.w;
            g1.x += b.x; g1.y += b.y; g1.z += b.z; g1.w += b.w;
        }
    }

    float lg[8] = { g0.x, g0.y, g0.z, g0.w,  g1.x, g1.y, g1.z, g1.w };

    float m = lg[0];
#pragma unroll
    for (int e = 1; e < 8; ++e) m = fmaxf(m, lg[e]);
#pragma unroll
    for (int off = 1; off <= 8; off <<= 1) m = fmaxf(m, __shfl_xor(m, off));

    float ssum = 0.f;
#pragma unroll
    for (int e = 0; e < 8; ++e) { lg[e] = __expf(lg[e] - m); ssum += lg[e]; }
#pragma unroll
    for (int off = 1; off <= 8; off <<= 1) ssum += __shfl_xor(ssum, off);
    const float inv = 1.f / ssum;

#pragma unroll
    for (int e = 0; e < 8; ++e) At[wl][s * 8 + e] = lg[e] * inv;

    // ---- land Vs into LDS, sync ----
#pragma unroll
    for (int r = 0; r < 2; ++r) {
        int L  = tid + r * 1024;
        int c  = L >> 5;
        int k4 = (L & 31) << 2;
        *(float4*)(&Vl[c][k4]) = vstage[r];
    }
    __syncthreads();

    // ---- phase B: out[c, h, w0+w2] = sum_kk At[w2][kk] * Vl[c][kk] ----
    const int w2 = tid & 63;
    const int c0 = __builtin_amdgcn_readfirstlane((tid >> 6) * 4);

    float acc[4];
#pragma unroll
    for (int j = 0; j < 4; ++j) acc[j] = 0.f;

    for (int kk = 0; kk < 128; kk += 4) {
        float4 a = *(const float4*)(&At[w2][kk]);
#pragma unroll
        for (int j = 0; j < 4; ++j) {
            float4 vv = *(const float4*)(&Vl[c0 + j][kk]);   // broadcast
            acc[j] += a.x * vv.x + a.y * vv.y + a.z * vv.z + a.w * vv.w;
        }
    }

#pragma unroll
    for (int j = 0; j < 4; ++j)
        out[(size_t)(c0 + j) * NPIX + h * W + w0 + w2] = acc[j];
}

// ---------------------------------------------------------------------------
// Workspace: 6M floats = 24 MB used, non-overlapping:
//   qT [0,1M)  k [1M,2M)  v [2M,3M)  Sd [3M,5M)  Vs [5M,6M)
// ---------------------------------------------------------------------------
extern "C" void kernel_launch(void* const* d_in, const int* in_sizes, int n_in,
                              void* d_out, int out_size, void* d_ws, size_t ws_size,
                              hipStream_t stream)
{
    const float* x  = (const float*)d_in[0];
    const float* Wq = (const float*)d_in[1];
    const float* bq = (const float*)d_in[2];
    const float* Wk = (const float*)d_in[3];
    const float* bk = (const float*)d_in[4];
    const float* Wv = (const float*)d_in[5];
    const float* bv = (const float*)d_in[6];
    float* out = (float*)d_out;

    float* ws = (float*)d_ws;
    const size_t NQ = (size_t)C * NPIX;       // 1M floats
    const size_t NS = (size_t)H * W * W;      // 2M floats

    float* qT   = ws;
    float* k    = ws + NQ;
    float* v    = ws + 2 * NQ;
    float* Sd   = ws + 3 * NQ;
    float* Vsum = ws + 3 * NQ + NS;

    k_conv<<<dim3(NPIX / 64, 4), 256, 0, stream>>>(x, Wq, bq, Wk, bk, Wv, bv, qT, k, v);
    k_mid<<<dim3(1536), 256, 0, stream>>>(qT, k, v, Sd, Vsum);
    k_fused<<<dim3(H, 2), 1024, 0, stream>>>(Sd, Vsum, out);
}

// Round 10
// 136.720 us; speedup vs baseline: 1.1172x; 1.1172x over previous
//
#include <hip/hip_runtime.h>

static constexpr int C    = 64;
static constexpr int H    = 128;
static constexpr int W    = 128;
static constexpr int NPIX = H * W;      // 16384
static constexpr int PAD  = 3;          // WS=7 -> +-3

typedef float vf4 __attribute__((ext_vector_type(4)));   // NT-store-able

// ---------------------------------------------------------------------------
// 1) conv1x1, z-merged + NT stores (r8 exact, rotation reverted) + a
//    sched_barrier(0) pinning all 64 x-loads BEFORE the FMA loop.
//    r9's VGPR_Count=64 proved the compiler sinks the xr[] loads into the
//    FMA loop (serialized 64-deep load->FMA chain, the r0 signature) even
//    under (256,4). The barrier forces batch issue: latency paid once.
//    grid (NPIX/64, 4) = 1024 blocks -> 4 blocks/CU, 16 waves/CU.
// ---------------------------------------------------------------------------
__global__ __launch_bounds__(256, 4) void k_conv(
    const float* __restrict__ x,
    const float* __restrict__ Wq, const float* __restrict__ bq,
    const float* __restrict__ Wk, const float* __restrict__ bk,
    const float* __restrict__ Wv, const float* __restrict__ bv,
    float* __restrict__ qT, float* __restrict__ ko, float* __restrict__ vo)
{
    const int tid  = threadIdx.x;
    const int lane = tid & 63;
    const int p    = blockIdx.x * 64 + lane;
    const int o0   = __builtin_amdgcn_readfirstlane(
                         blockIdx.y * 16 + (tid >> 6) * 4);

    float xr[C];
#pragma unroll
    for (int c = 0; c < C; ++c) xr[c] = x[c * NPIX + p];

    // no instruction may cross: all 64 loads issued before any FMA below
    __builtin_amdgcn_sched_barrier(0);

    float aq[4], ak[4], av[4];
#pragma unroll
    for (int j = 0; j < 4; ++j) {
        aq[j] = bq[o0 + j];
        ak[j] = bk[o0 + j];
        av[j] = bv[o0 + j];
    }

#pragma unroll
    for (int c = 0; c < C; ++c) {
        const float xv = xr[c];
#pragma unroll
        for (int j = 0; j < 4; ++j) {
            aq[j] += Wq[(o0 + j) * C + c] * xv;
            ak[j] += Wk[(o0 + j) * C + c] * xv;
            av[j] += Wv[(o0 + j) * C + c] * xv;
        }
    }

    vf4 qv4 = { aq[0], aq[1], aq[2], aq[3] };
    __builtin_nontemporal_store(qv4, (vf4*)(qT + (size_t)p * C + o0));
#pragma unroll
    for (int j = 0; j < 4; ++j) {
        __builtin_nontemporal_store(ak[j], ko + (size_t)(o0 + j) * NPIX + p);
        __builtin_nontemporal_store(av[j], vo + (size_t)(o0 + j) * NPIX + p);
    }
}

// ---------------------------------------------------------------------------
// 2) merged dispatch: [gram+diag] (blocks 0..1023) and [7x7 box of v]
//    (blocks 1024..1535). r6/r8 form (rotation reverted) + sched_barrier(0)
//    pinning the 128 ks-loads before the j-loop (same sinking hazard).
// ---------------------------------------------------------------------------
__global__ __launch_bounds__(256, 3) void k_mid(
    const float* __restrict__ qT, const float* __restrict__ kmat,
    const float* __restrict__ v,
    float* __restrict__ Sd, float* __restrict__ Vs)
{
    __shared__ union {
        struct { float Sl[22][130]; float qs[22][64]; } g;   // 16.7 KB
        struct { float vt[22][128]; float vh[22][128]; } box; // 22.5 KB
    } u;
    const int bid = blockIdx.x;
    const int tid = threadIdx.x;

    if (bid < 1024) {
        // ----- fused row-Gram + diagonal 7-sum -----
        const int h   = bid >> 3;
        const int w0  = (bid & 7) * 16;

        // stage q rows w0-3 .. w0+18 (zero-filled outside [0,W))
        for (int i = tid; i < 22 * 16; i += 256) {
            int r  = i >> 4, c4 = (i & 15) << 2;
            int wp = w0 - 3 + r;
            float4 qv = make_float4(0.f, 0.f, 0.f, 0.f);
            if (wp >= 0 && wp < W)
                qv = *(const float4*)(qT + (size_t)(h * W + wp) * C + c4);
            *(float4*)(&u.g.qs[r][c4]) = qv;
        }

        // two k-columns per thread: kkt and kkt+64 (coalesced loads)
        const int kkt = tid & 63;
        const int g   = tid >> 6;            // 0..3, wave-uniform row group
        float ks0[C], ks1[C];
#pragma unroll
        for (int c = 0; c < C; ++c) {
            ks0[c] = kmat[c * NPIX + h * W + kkt];
            ks1[c] = kmat[c * NPIX + h * W + kkt + 64];
        }
        // pin: all 128 k-loads in flight before the compute loop
        __builtin_amdgcn_sched_barrier(0);
        __syncthreads();

        for (int j = 0; j < 6; ++j) {
            int row = g * 6 + j;             // 0..23, wave-uniform
            if (row < 22) {                  // wave-uniform branch
                float a0 = 0.f, a1 = 0.f, a2 = 0.f, a3 = 0.f;
                float b0 = 0.f, b1 = 0.f, b2 = 0.f, b3 = 0.f;
#pragma unroll
                for (int c = 0; c < C; c += 4) {
                    float4 qv = *(const float4*)(&u.g.qs[row][c]); // broadcast
                    a0 += qv.x * ks0[c + 0];  b0 += qv.x * ks1[c + 0];
                    a1 += qv.y * ks0[c + 1];  b1 += qv.y * ks1[c + 1];
                    a2 += qv.z * ks0[c + 2];  b2 += qv.z * ks1[c + 2];
                    a3 += qv.w * ks0[c + 3];  b3 += qv.w * ks1[c + 3];
                }
                u.g.Sl[row][kkt]      = (a0 + a1) + (a2 + a3);
                u.g.Sl[row][kkt + 64] = (b0 + b1) + (b2 + b3);
            }
        }
        __syncthreads();

        // ----- diagonal 7-sum (unchanged) -----
        const int kk  = tid & 127;
        const int wsl = tid >> 7;            // 0/1, wave-uniform
#pragma unroll
        for (int r = 0; r < 8; ++r) {
            int wl = wsl * 8 + r;            // 0..15
            float a = 0.f;
#pragma unroll
            for (int dd = -PAD; dd <= PAD; ++dd) {
                int kj = kk + dd;
                if (kj >= 0 && kj < W)
                    a += u.g.Sl[wl + 3 + dd][kj];
            }
            Sd[(size_t)(h * W + w0 + wl) * W + kk] = a;
        }
    } else {
        // ----- 7x7 box sum of v (separable in LDS, unchanged) -----
        const int b2 = bid - 1024;           // 0..511
        const int c  = b2 >> 3;              // 0..63
        const int h0 = (b2 & 7) * 16;

        for (int i = tid; i < 22 * 128; i += 256) {
            int r = i >> 7, w = i & 127;
            int h = h0 - 3 + r;
            u.box.vt[r][w] = (h >= 0 && h < H) ? v[c * NPIX + h * W + w] : 0.f;
        }
        __syncthreads();
        for (int i = tid; i < 22 * 128; i += 256) {
            int r = i >> 7, w = i & 127;
            float s = 0.f;
#pragma unroll
            for (int d = -PAD; d <= PAD; ++d) {
                int wj = w + d;
                if (wj >= 0 && wj < W) s += u.box.vt[r][wj];
            }
            u.box.vh[r][w] = s;
        }
        __syncthreads();
        for (int i = tid; i < 16 * 128; i += 256) {
            int r = i >> 7, w = i & 127;
            float s = 0.f;
#pragma unroll
            for (int d = 0; d < 7; ++d) s += u.box.vh[r + d][w];
            Vs[c * NPIX + (h0 + r) * W + w] = s;
        }
    }
}

// ---------------------------------------------------------------------------
// 3) FUSED vertical-7-sum + softmax + PV, 1024-thread version (r5 exact)
//    + sched_barrier(0) pinning the early Vs loads before phase A (prevents
//    the compiler sinking them to their use point after the softmax).
// ---------------------------------------------------------------------------
__global__ __launch_bounds__(1024, 4) void k_fused(
    const float* __restrict__ Sd, const float* __restrict__ Vs,
    float* __restrict__ out)
{
    constexpr int AP = 129;          // attn LDS pitch
    __shared__ float At[64][AP];     // attn[w-local][kk], 33.0 KB
    __shared__ float Vl[64][128];    // Vs[c][kk],         32.8 KB

    const int h   = blockIdx.x;
    const int w0  = blockIdx.y * 64;
    const int tid = threadIdx.x;

    // ---- issue Vs staging loads early (consumed after phase A) ----
    float4 vstage[2];
#pragma unroll
    for (int r = 0; r < 2; ++r) {
        int L  = tid + r * 1024;         // 0..2047 float4 tiles
        int c  = L >> 5;                 // 32 float4 per channel row
        int k4 = (L & 31) << 2;
        vstage[r] = *(const float4*)(Vs + (size_t)c * NPIX + h * W + k4);
    }
    __builtin_amdgcn_sched_barrier(0);   // keep them in flight during phase A

    // ---- phase A: logits (vertical 7-sum of Sd) + softmax into LDS ----
    const int wl = tid >> 4;             // 0..63 (w within half)
    const int s  = tid & 15;             // kk-16th: kk = s*8 + e

    float4 g0 = make_float4(0.f, 0.f, 0.f, 0.f);
    float4 g1 = g0;
#pragma unroll
    for (int i = 0; i < 7; ++i) {
        int hp = h - 3 + i;              // block-uniform branch
        if (hp >= 0 && hp < H) {
            const float4* src = (const float4*)(
                Sd + (size_t)hp * NPIX + (w0 + wl) * W + s * 8);
            float4 a = src[0], b = src[1];
            g0.x += a.x; g0.y += a.y; g0.z += a.z; g0.w += a.w;
            g1.x += b.x; g1.y += b.y; g1.z += b.z; g1.w += b.w;
        }
    }

    float lg[8] = { g0.x, g0.y, g0.z, g0.w,  g1.x, g1.y, g1.z, g1.w };

    float m = lg[0];
#pragma unroll
    for (int e = 1; e < 8; ++e) m = fmaxf(m, lg[e]);
#pragma unroll
    for (int off = 1; off <= 8; off <<= 1) m = fmaxf(m, __shfl_xor(m, off));

    float ssum = 0.f;
#pragma unroll
    for (int e = 0; e < 8; ++e) { lg[e] = __expf(lg[e] - m); ssum += lg[e]; }
#pragma unroll
    for (int off = 1; off <= 8; off <<= 1) ssum += __shfl_xor(ssum, off);
    const float inv = 1.f / ssum;

#pragma unroll
    for (int e = 0; e < 8; ++e) At[wl][s * 8 + e] = lg[e] * inv;

    // ---- land Vs into LDS, sync ----
#pragma unroll
    for (int r = 0; r < 2; ++r) {
        int L  = tid + r * 1024;
        int c  = L >> 5;
        int k4 = (L & 31) << 2;
        *(float4*)(&Vl[c][k4]) = vstage[r];
    }
    __syncthreads();

    // ---- phase B: out[c, h, w0+w2] = sum_kk At[w2][kk] * Vl[c][kk] ----
    const int w2 = tid & 63;
    const int c0 = __builtin_amdgcn_readfirstlane((tid >> 6) * 4);

    float acc[4];
#pragma unroll
    for (int j = 0; j < 4; ++j) acc[j] = 0.f;

    for (int kk = 0; kk < 128; kk += 4) {
        float4 a = *(const float4*)(&At[w2][kk]);
#pragma unroll
        for (int j = 0; j < 4; ++j) {
            float4 vv = *(const float4*)(&Vl[c0 + j][kk]);   // broadcast
            acc[j] += a.x * vv.x + a.y * vv.y + a.z * vv.z + a.w * vv.w;
        }
    }

#pragma unroll
    for (int j = 0; j < 4; ++j)
        out[(size_t)(c0 + j) * NPIX + h * W + w0 + w2] = acc[j];
}

// ---------------------------------------------------------------------------
// Workspace: 6M floats = 24 MB used, non-overlapping:
//   qT [0,1M)  k [1M,2M)  v [2M,3M)  Sd [3M,5M)  Vs [5M,6M)
// ---------------------------------------------------------------------------
extern "C" void kernel_launch(void* const* d_in, const int* in_sizes, int n_in,
                              void* d_out, int out_size, void* d_ws, size_t ws_size,
                              hipStream_t stream)
{
    const float* x  = (const float*)d_in[0];
    const float* Wq = (const float*)d_in[1];
    const float* bq = (const float*)d_in[2];
    const float* Wk = (const float*)d_in[3];
    const float* bk = (const float*)d_in[4];
    const float* Wv = (const float*)d_in[5];
    const float* bv = (const float*)d_in[6];
    float* out = (float*)d_out;

    float* ws = (float*)d_ws;
    const size_t NQ = (size_t)C * NPIX;       // 1M floats
    const size_t NS = (size_t)H * W * W;      // 2M floats

    float* qT   = ws;
    float* k    = ws + NQ;
    float* v    = ws + 2 * NQ;
    float* Sd   = ws + 3 * NQ;
    float* Vsum = ws + 3 * NQ + NS;

    k_conv<<<dim3(NPIX / 64, 4), 256, 0, stream>>>(x, Wq, bq, Wk, bk, Wv, bv, qT, k, v);
    k_mid<<<dim3(1536), 256, 0, stream>>>(qT, k, v, Sd, Vsum);
    k_fused<<<dim3(H, 2), 1024, 0, stream>>>(Sd, Vsum, out);
}

// Round 11
// 122.929 us; speedup vs baseline: 1.2426x; 1.1122x over previous
//
#include <hip/hip_runtime.h>

static constexpr int C    = 64;
static constexpr int H    = 128;
static constexpr int W    = 128;
static constexpr int NPIX = H * W;      // 16384
static constexpr int PAD  = 3;          // WS=7 -> +-3

typedef float vf4 __attribute__((ext_vector_type(4)));   // NT-store-able

// ---------------------------------------------------------------------------
// 1) conv1x1, LDS-staged-x version. The structural fix for the r0/r4/r9/r10
//    conv saga: NO per-thread xr[64] array (the compiler either sinks it ->
//    serialized chain, or batch-issues 64 strided loads -> exposed vmcnt
//    drain). Instead: stage the 64px x 64ch x-tile (16 KB) with coalesced
//    float4 loads (16/thread), consume via ds_read_b32 xs[c][lane]
//    (2-lane/bank = conflict-free; compiler pipelines lgkmcnt).
//    W stays on the s_load path (r4 lesson). NT stores (r8, proven neutral+).
//    grid (256, 4) = 1024 blocks -> 4 blocks/CU, 16 waves/CU. VGPR ~50.
// ---------------------------------------------------------------------------
__global__ __launch_bounds__(256, 4) void k_conv(
    const float* __restrict__ x,
    const float* __restrict__ Wq, const float* __restrict__ bq,
    const float* __restrict__ Wk, const float* __restrict__ bk,
    const float* __restrict__ Wv, const float* __restrict__ bv,
    float* __restrict__ qT, float* __restrict__ ko, float* __restrict__ vo)
{
    __shared__ float xs[64][64];         // 16 KB, pitch 64: col reads 2-way ok
    const int tid  = threadIdx.x;
    const int lane = tid & 63;
    const int p0   = blockIdx.x * 64;
    const int p    = p0 + lane;
    const int o0   = __builtin_amdgcn_readfirstlane(
                         blockIdx.y * 16 + (tid >> 6) * 4);

    // ---- stage x tile: 1024 float4 / 256 thr = 4 each, fully coalesced ----
#pragma unroll
    for (int r = 0; r < 4; ++r) {
        int f  = tid + r * 256;          // 0..1023
        int c  = f >> 4;                 // 16 float4 per channel row
        int i4 = (f & 15) << 2;
        *(float4*)(&xs[c][i4]) =
            *(const float4*)(x + (size_t)c * NPIX + p0 + i4);
    }
    __syncthreads();

    float aq[4], ak[4], av[4];
#pragma unroll
    for (int j = 0; j < 4; ++j) {
        aq[j] = bq[o0 + j];
        ak[j] = bk[o0 + j];
        av[j] = bv[o0 + j];
    }

#pragma unroll
    for (int c = 0; c < C; ++c) {
        const float xv = xs[c][lane];    // ds_read_b32, conflict-free
#pragma unroll
        for (int j = 0; j < 4; ++j) {
            aq[j] += Wq[(o0 + j) * C + c] * xv;   // W: wave-uniform s_load
            ak[j] += Wk[(o0 + j) * C + c] * xv;
            av[j] += Wv[(o0 + j) * C + c] * xv;
        }
    }

    vf4 qv4 = { aq[0], aq[1], aq[2], aq[3] };
    __builtin_nontemporal_store(qv4, (vf4*)(qT + (size_t)p * C + o0));
#pragma unroll
    for (int j = 0; j < 4; ++j) {
        __builtin_nontemporal_store(ak[j], ko + (size_t)(o0 + j) * NPIX + p);
        __builtin_nontemporal_store(av[j], vo + (size_t)(o0 + j) * NPIX + p);
    }
}

// ---------------------------------------------------------------------------
// 2) merged dispatch: [gram+diag] (blocks 0..1023) and [7x7 box of v]
//    (blocks 1024..1535). r8 exact (sched_barrier removed - r10 regression).
// ---------------------------------------------------------------------------
__global__ __launch_bounds__(256, 3) void k_mid(
    const float* __restrict__ qT, const float* __restrict__ kmat,
    const float* __restrict__ v,
    float* __restrict__ Sd, float* __restrict__ Vs)
{
    __shared__ union {
        struct { float Sl[22][130]; float qs[22][64]; } g;   // 16.7 KB
        struct { float vt[22][128]; float vh[22][128]; } box; // 22.5 KB
    } u;
    const int bid = blockIdx.x;
    const int tid = threadIdx.x;

    if (bid < 1024) {
        // ----- fused row-Gram + diagonal 7-sum -----
        const int h   = bid >> 3;
        const int w0  = (bid & 7) * 16;

        // stage q rows w0-3 .. w0+18 (zero-filled outside [0,W))
        for (int i = tid; i < 22 * 16; i += 256) {
            int r  = i >> 4, c4 = (i & 15) << 2;
            int wp = w0 - 3 + r;
            float4 qv = make_float4(0.f, 0.f, 0.f, 0.f);
            if (wp >= 0 && wp < W)
                qv = *(const float4*)(qT + (size_t)(h * W + wp) * C + c4);
            *(float4*)(&u.g.qs[r][c4]) = qv;
        }

        // two k-columns per thread: kkt and kkt+64 (coalesced loads)
        const int kkt = tid & 63;
        const int g   = tid >> 6;            // 0..3, wave-uniform row group
        float ks0[C], ks1[C];
#pragma unroll
        for (int c = 0; c < C; ++c) {
            ks0[c] = kmat[c * NPIX + h * W + kkt];
            ks1[c] = kmat[c * NPIX + h * W + kkt + 64];
        }
        __syncthreads();

        for (int j = 0; j < 6; ++j) {
            int row = g * 6 + j;             // 0..23, wave-uniform
            if (row < 22) {                  // wave-uniform branch
                float a0 = 0.f, a1 = 0.f, a2 = 0.f, a3 = 0.f;
                float b0 = 0.f, b1 = 0.f, b2 = 0.f, b3 = 0.f;
#pragma unroll
                for (int c = 0; c < C; c += 4) {
                    float4 qv = *(const float4*)(&u.g.qs[row][c]); // broadcast
                    a0 += qv.x * ks0[c + 0];  b0 += qv.x * ks1[c + 0];
                    a1 += qv.y * ks0[c + 1];  b1 += qv.y * ks1[c + 1];
                    a2 += qv.z * ks0[c + 2];  b2 += qv.z * ks1[c + 2];
                    a3 += qv.w * ks0[c + 3];  b3 += qv.w * ks1[c + 3];
                }
                u.g.Sl[row][kkt]      = (a0 + a1) + (a2 + a3);
                u.g.Sl[row][kkt + 64] = (b0 + b1) + (b2 + b3);
            }
        }
        __syncthreads();

        // ----- diagonal 7-sum (unchanged) -----
        const int kk  = tid & 127;
        const int wsl = tid >> 7;            // 0/1, wave-uniform
#pragma unroll
        for (int r = 0; r < 8; ++r) {
            int wl = wsl * 8 + r;            // 0..15
            float a = 0.f;
#pragma unroll
            for (int dd = -PAD; dd <= PAD; ++dd) {
                int kj = kk + dd;
                if (kj >= 0 && kj < W)
                    a += u.g.Sl[wl + 3 + dd][kj];
            }
            Sd[(size_t)(h * W + w0 + wl) * W + kk] = a;
        }
    } else {
        // ----- 7x7 box sum of v (separable in LDS, unchanged) -----
        const int b2 = bid - 1024;           // 0..511
        const int c  = b2 >> 3;              // 0..63
        const int h0 = (b2 & 7) * 16;

        for (int i = tid; i < 22 * 128; i += 256) {
            int r = i >> 7, w = i & 127;
            int h = h0 - 3 + r;
            u.box.vt[r][w] = (h >= 0 && h < H) ? v[c * NPIX + h * W + w] : 0.f;
        }
        __syncthreads();
        for (int i = tid; i < 22 * 128; i += 256) {
            int r = i >> 7, w = i & 127;
            float s = 0.f;
#pragma unroll
            for (int d = -PAD; d <= PAD; ++d) {
                int wj = w + d;
                if (wj >= 0 && wj < W) s += u.box.vt[r][wj];
            }
            u.box.vh[r][w] = s;
        }
        __syncthreads();
        for (int i = tid; i < 16 * 128; i += 256) {
            int r = i >> 7, w = i & 127;
            float s = 0.f;
#pragma unroll
            for (int d = 0; d < 7; ++d) s += u.box.vh[r + d][w];
            Vs[c * NPIX + (h0 + r) * W + w] = s;
        }
    }
}

// ---------------------------------------------------------------------------
// 3) FUSED vertical-7-sum + softmax + PV, 1024-thread version. r5 exact
//    (sched_barrier removed). grid (H, 2) x 1024 thr; 32 waves/CU.
// ---------------------------------------------------------------------------
__global__ __launch_bounds__(1024, 4) void k_fused(
    const float* __restrict__ Sd, const float* __restrict__ Vs,
    float* __restrict__ out)
{
    constexpr int AP = 129;          // attn LDS pitch
    __shared__ float At[64][AP];     // attn[w-local][kk], 33.0 KB
    __shared__ float Vl[64][128];    // Vs[c][kk],         32.8 KB

    const int h   = blockIdx.x;
    const int w0  = blockIdx.y * 64;
    const int tid = threadIdx.x;

    // ---- issue Vs staging loads early (consumed after phase A) ----
    float4 vstage[2];
#pragma unroll
    for (int r = 0; r < 2; ++r) {
        int L  = tid + r * 1024;         // 0..2047 float4 tiles
        int c  = L >> 5;                 // 32 float4 per channel row
        int k4 = (L & 31) << 2;
        vstage[r] = *(const float4*)(Vs + (size_t)c * NPIX + h * W + k4);
    }

    // ---- phase A: logits (vertical 7-sum of Sd) + softmax into LDS ----
    const int wl = tid >> 4;             // 0..63 (w within half)
    const int s  = tid & 15;             // kk-16th: kk = s*8 + e

    float4 g0 = make_float4(0.f, 0.f, 0.f, 0.f);
    float4 g1 = g0;
#pragma unroll
    for (int i = 0; i < 7; ++i) {
        int hp = h - 3 + i;              // block-uniform branch
        if (hp >= 0 && hp < H) {
            const float4* src = (const float4*)(
                Sd + (size_t)hp * NPIX + (w0 + wl) * W + s * 8);
            float4 a = src[0], b = src[1];
            g0.x += a.x; g0.y += a.y; g0.z += a.z; g0.w += a.w;
            g1.x += b.x; g1.y += b.y; g1.z += b.z; g1.w += b.w;
        }
    }

    float lg[8] = { g0.x, g0.y, g0.z, g0.w,  g1.x, g1.y, g1.z, g1.w };

    float m = lg[0];
#pragma unroll
    for (int e = 1; e < 8; ++e) m = fmaxf(m, lg[e]);
#pragma unroll
    for (int off = 1; off <= 8; off <<= 1) m = fmaxf(m, __shfl_xor(m, off));

    float ssum = 0.f;
#pragma unroll
    for (int e = 0; e < 8; ++e) { lg[e] = __expf(lg[e] - m); ssum += lg[e]; }
#pragma unroll
    for (int off = 1; off <= 8; off <<= 1) ssum += __shfl_xor(ssum, off);
    const float inv = 1.f / ssum;

#pragma unroll
    for (int e = 0; e < 8; ++e) At[wl][s * 8 + e] = lg[e] * inv;

    // ---- land Vs into LDS, sync ----
#pragma unroll
    for (int r = 0; r < 2; ++r) {
        int L  = tid + r * 1024;
        int c  = L >> 5;
        int k4 = (L & 31) << 2;
        *(float4*)(&Vl[c][k4]) = vstage[r];
    }
    __syncthreads();

    // ---- phase B: out[c, h, w0+w2] = sum_kk At[w2][kk] * Vl[c][kk] ----
    const int w2 = tid & 63;
    const int c0 = __builtin_amdgcn_readfirstlane((tid >> 6) * 4);

    float acc[4];
#pragma unroll
    for (int j = 0; j < 4; ++j) acc[j] = 0.f;

    for (int kk = 0; kk < 128; kk += 4) {
        float4 a = *(const float4*)(&At[w2][kk]);
#pragma unroll
        for (int j = 0; j < 4; ++j) {
            float4 vv = *(const float4*)(&Vl[c0 + j][kk]);   // broadcast
            acc[j] += a.x * vv.x + a.y * vv.y + a.z * vv.z + a.w * vv.w;
        }
    }

#pragma unroll
    for (int j = 0; j < 4; ++j)
        out[(size_t)(c0 + j) * NPIX + h * W + w0 + w2] = acc[j];
}

// ---------------------------------------------------------------------------
// Workspace: 6M floats = 24 MB used, non-overlapping:
//   qT [0,1M)  k [1M,2M)  v [2M,3M)  Sd [3M,5M)  Vs [5M,6M)
// ---------------------------------------------------------------------------
extern "C" void kernel_launch(void* const* d_in, const int* in_sizes, int n_in,
                              void* d_out, int out_size, void* d_ws, size_t ws_size,
                              hipStream_t stream)
{
    const float* x  = (const float*)d_in[0];
    const float* Wq = (const float*)d_in[1];
    const float* bq = (const float*)d_in[2];
    const float* Wk = (const float*)d_in[3];
    const float* bk = (const float*)d_in[4];
    const float* Wv = (const float*)d_in[5];
    const float* bv = (const float*)d_in[6];
    float* out = (float*)d_out;

    float* ws = (float*)d_ws;
    const size_t NQ = (size_t)C * NPIX;       // 1M floats
    const size_t NS = (size_t)H * W * W;      // 2M floats

    float* qT   = ws;
    float* k    = ws + NQ;
    float* v    = ws + 2 * NQ;
    float* Sd   = ws + 3 * NQ;
    float* Vsum = ws + 3 * NQ + NS;

    k_conv<<<dim3(NPIX / 64, 4), 256, 0, stream>>>(x, Wq, bq, Wk, bk, Wv, bv, qT, k, v);
    k_mid<<<dim3(1536), 256, 0, stream>>>(qT, k, v, Sd, Vsum);
    k_fused<<<dim3(H, 2), 1024, 0, stream>>>(Sd, Vsum, out);
}

// Round 12
// 122.760 us; speedup vs baseline: 1.2443x; 1.0014x over previous
//
#include <hip/hip_runtime.h>

static constexpr int C    = 64;
static constexpr int H    = 128;
static constexpr int W    = 128;
static constexpr int NPIX = H * W;      // 16384
static constexpr int PAD  = 3;          // WS=7 -> +-3

typedef float vf4 __attribute__((ext_vector_type(4)));   // NT-store-able

// ---------------------------------------------------------------------------
// 1) conv1x1, LDS-staged-x version. [r11 exact]
//    grid (256, 4) = 1024 blocks -> 4 blocks/CU, 16 waves/CU.
// ---------------------------------------------------------------------------
__global__ __launch_bounds__(256, 4) void k_conv(
    const float* __restrict__ x,
    const float* __restrict__ Wq, const float* __restrict__ bq,
    const float* __restrict__ Wk, const float* __restrict__ bk,
    const float* __restrict__ Wv, const float* __restrict__ bv,
    float* __restrict__ qT, float* __restrict__ ko, float* __restrict__ vo)
{
    __shared__ float xs[64][64];         // 16 KB
    const int tid  = threadIdx.x;
    const int lane = tid & 63;
    const int p0   = blockIdx.x * 64;
    const int p    = p0 + lane;
    const int o0   = __builtin_amdgcn_readfirstlane(
                         blockIdx.y * 16 + (tid >> 6) * 4);

#pragma unroll
    for (int r = 0; r < 4; ++r) {
        int f  = tid + r * 256;          // 0..1023
        int c  = f >> 4;                 // 16 float4 per channel row
        int i4 = (f & 15) << 2;
        *(float4*)(&xs[c][i4]) =
            *(const float4*)(x + (size_t)c * NPIX + p0 + i4);
    }
    __syncthreads();

    float aq[4], ak[4], av[4];
#pragma unroll
    for (int j = 0; j < 4; ++j) {
        aq[j] = bq[o0 + j];
        ak[j] = bk[o0 + j];
        av[j] = bv[o0 + j];
    }

#pragma unroll
    for (int c = 0; c < C; ++c) {
        const float xv = xs[c][lane];    // ds_read_b32, conflict-free
#pragma unroll
        for (int j = 0; j < 4; ++j) {
            aq[j] += Wq[(o0 + j) * C + c] * xv;   // W: wave-uniform s_load
            ak[j] += Wk[(o0 + j) * C + c] * xv;
            av[j] += Wv[(o0 + j) * C + c] * xv;
        }
    }

    vf4 qv4 = { aq[0], aq[1], aq[2], aq[3] };
    __builtin_nontemporal_store(qv4, (vf4*)(qT + (size_t)p * C + o0));
#pragma unroll
    for (int j = 0; j < 4; ++j) {
        __builtin_nontemporal_store(ak[j], ko + (size_t)(o0 + j) * NPIX + p);
        __builtin_nontemporal_store(av[j], vo + (size_t)(o0 + j) * NPIX + p);
    }
}

// ---------------------------------------------------------------------------
// 2) merged dispatch: [gram+diag] (blocks 0..1023) and [7x7 box of v]
//    (blocks 1024..1535). [r11/r8 exact]
// ---------------------------------------------------------------------------
__global__ __launch_bounds__(256, 3) void k_mid(
    const float* __restrict__ qT, const float* __restrict__ kmat,
    const float* __restrict__ v,
    float* __restrict__ Sd, float* __restrict__ Vs)
{
    __shared__ union {
        struct { float Sl[22][130]; float qs[22][64]; } g;   // 16.7 KB
        struct { float vt[22][128]; float vh[22][128]; } box; // 22.5 KB
    } u;
    const int bid = blockIdx.x;
    const int tid = threadIdx.x;

    if (bid < 1024) {
        // ----- fused row-Gram + diagonal 7-sum -----
        const int h   = bid >> 3;
        const int w0  = (bid & 7) * 16;

        // stage q rows w0-3 .. w0+18 (zero-filled outside [0,W))
        for (int i = tid; i < 22 * 16; i += 256) {
            int r  = i >> 4, c4 = (i & 15) << 2;
            int wp = w0 - 3 + r;
            float4 qv = make_float4(0.f, 0.f, 0.f, 0.f);
            if (wp >= 0 && wp < W)
                qv = *(const float4*)(qT + (size_t)(h * W + wp) * C + c4);
            *(float4*)(&u.g.qs[r][c4]) = qv;
        }

        // two k-columns per thread: kkt and kkt+64 (coalesced loads)
        const int kkt = tid & 63;
        const int g   = tid >> 6;            // 0..3, wave-uniform row group
        float ks0[C], ks1[C];
#pragma unroll
        for (int c = 0; c < C; ++c) {
            ks0[c] = kmat[c * NPIX + h * W + kkt];
            ks1[c] = kmat[c * NPIX + h * W + kkt + 64];
        }
        __syncthreads();

        for (int j = 0; j < 6; ++j) {
            int row = g * 6 + j;             // 0..23, wave-uniform
            if (row < 22) {                  // wave-uniform branch
                float a0 = 0.f, a1 = 0.f, a2 = 0.f, a3 = 0.f;
                float b0 = 0.f, b1 = 0.f, b2 = 0.f, b3 = 0.f;
#pragma unroll
                for (int c = 0; c < C; c += 4) {
                    float4 qv = *(const float4*)(&u.g.qs[row][c]); // broadcast
                    a0 += qv.x * ks0[c + 0];  b0 += qv.x * ks1[c + 0];
                    a1 += qv.y * ks0[c + 1];  b1 += qv.y * ks1[c + 1];
                    a2 += qv.z * ks0[c + 2];  b2 += qv.z * ks1[c + 2];
                    a3 += qv.w * ks0[c + 3];  b3 += qv.w * ks1[c + 3];
                }
                u.g.Sl[row][kkt]      = (a0 + a1) + (a2 + a3);
                u.g.Sl[row][kkt + 64] = (b0 + b1) + (b2 + b3);
            }
        }
        __syncthreads();

        // ----- diagonal 7-sum (unchanged) -----
        const int kk  = tid & 127;
        const int wsl = tid >> 7;            // 0/1, wave-uniform
#pragma unroll
        for (int r = 0; r < 8; ++r) {
            int wl = wsl * 8 + r;            // 0..15
            float a = 0.f;
#pragma unroll
            for (int dd = -PAD; dd <= PAD; ++dd) {
                int kj = kk + dd;
                if (kj >= 0 && kj < W)
                    a += u.g.Sl[wl + 3 + dd][kj];
            }
            Sd[(size_t)(h * W + w0 + wl) * W + kk] = a;
        }
    } else {
        // ----- 7x7 box sum of v (separable in LDS, unchanged) -----
        const int b2 = bid - 1024;           // 0..511
        const int c  = b2 >> 3;              // 0..63
        const int h0 = (b2 & 7) * 16;

        for (int i = tid; i < 22 * 128; i += 256) {
            int r = i >> 7, w = i & 127;
            int h = h0 - 3 + r;
            u.box.vt[r][w] = (h >= 0 && h < H) ? v[c * NPIX + h * W + w] : 0.f;
        }
        __syncthreads();
        for (int i = tid; i < 22 * 128; i += 256) {
            int r = i >> 7, w = i & 127;
            float s = 0.f;
#pragma unroll
            for (int d = -PAD; d <= PAD; ++d) {
                int wj = w + d;
                if (wj >= 0 && wj < W) s += u.box.vt[r][wj];
            }
            u.box.vh[r][w] = s;
        }
        __syncthreads();
        for (int i = tid; i < 16 * 128; i += 256) {
            int r = i >> 7, w = i & 127;
            float s = 0.f;
#pragma unroll
            for (int d = 0; d < 7; ++d) s += u.box.vh[r + d][w];
            Vs[c * NPIX + (h0 + r) * W + w] = s;
        }
    }
}

// ---------------------------------------------------------------------------
// 3) FUSED vertical-7-sum + softmax + PV. THIS ROUND'S single variable:
//    phase B reads Vs via WAVE-UNIFORM loads straight from global (address
//    = f(readfirstlane c0, h, loop-const kk) -> scalar/VMEM pipe), killing
//    the Vl LDS array + vstage. LDS insts/thread: 160 -> 32 (At only).
//    Rationale: r5's occupancy-doubling neutrality = LDS-pipe saturation
//    (32 waves x 160 b128 x ~12cyc ~ 25 us/CU). Vs row is L2/L3-hot (4 MB,
//    written by k_mid). LDS 65.8 -> 33 KB. grid (H,2) x 1024 thr.
// ---------------------------------------------------------------------------
__global__ __launch_bounds__(1024, 4) void k_fused(
    const float* __restrict__ Sd, const float* __restrict__ Vs,
    float* __restrict__ out)
{
    constexpr int AP = 129;          // attn LDS pitch
    __shared__ float At[64][AP];     // attn[w-local][kk], 33.0 KB

    const int h   = blockIdx.x;
    const int w0  = blockIdx.y * 64;
    const int tid = threadIdx.x;

    // ---- phase A: logits (vertical 7-sum of Sd) + softmax into LDS ----
    const int wl = tid >> 4;             // 0..63 (w within half)
    const int s  = tid & 15;             // kk-16th: kk = s*8 + e

    float4 g0 = make_float4(0.f, 0.f, 0.f, 0.f);
    float4 g1 = g0;
#pragma unroll
    for (int i = 0; i < 7; ++i) {
        int hp = h - 3 + i;              // block-uniform branch
        if (hp >= 0 && hp < H) {
            const float4* src = (const float4*)(
                Sd + (size_t)hp * NPIX + (w0 + wl) * W + s * 8);
            float4 a = src[0], b = src[1];
            g0.x += a.x; g0.y += a.y; g0.z += a.z; g0.w += a.w;
            g1.x += b.x; g1.y += b.y; g1.z += b.z; g1.w += b.w;
        }
    }

    float lg[8] = { g0.x, g0.y, g0.z, g0.w,  g1.x, g1.y, g1.z, g1.w };

    float m = lg[0];
#pragma unroll
    for (int e = 1; e < 8; ++e) m = fmaxf(m, lg[e]);
#pragma unroll
    for (int off = 1; off <= 8; off <<= 1) m = fmaxf(m, __shfl_xor(m, off));

    float ssum = 0.f;
#pragma unroll
    for (int e = 0; e < 8; ++e) { lg[e] = __expf(lg[e] - m); ssum += lg[e]; }
#pragma unroll
    for (int off = 1; off <= 8; off <<= 1) ssum += __shfl_xor(ssum, off);
    const float inv = 1.f / ssum;

#pragma unroll
    for (int e = 0; e < 8; ++e) At[wl][s * 8 + e] = lg[e] * inv;

    __syncthreads();

    // ---- phase B: out[c, h, w0+w2] = sum_kk At[w2][kk] * Vs[c][h][kk] ----
    const int w2 = tid & 63;
    const int c0 = __builtin_amdgcn_readfirstlane((tid >> 6) * 4);

    // wave-uniform row bases -> scalar loads (off the LDS pipe)
    const float* __restrict__ vr0 = Vs + (size_t)(c0 + 0) * NPIX + h * W;
    const float* __restrict__ vr1 = Vs + (size_t)(c0 + 1) * NPIX + h * W;
    const float* __restrict__ vr2 = Vs + (size_t)(c0 + 2) * NPIX + h * W;
    const float* __restrict__ vr3 = Vs + (size_t)(c0 + 3) * NPIX + h * W;

    float acc[4];
#pragma unroll
    for (int j = 0; j < 4; ++j) acc[j] = 0.f;

#pragma unroll 4
    for (int kk = 0; kk < 128; kk += 4) {
        float4 a  = *(const float4*)(&At[w2][kk]);        // only LDS read
        float4 v0 = *(const float4*)(vr0 + kk);           // uniform loads
        float4 v1 = *(const float4*)(vr1 + kk);
        float4 v2 = *(const float4*)(vr2 + kk);
        float4 v3 = *(const float4*)(vr3 + kk);
        acc[0] += a.x * v0.x + a.y * v0.y + a.z * v0.z + a.w * v0.w;
        acc[1] += a.x * v1.x + a.y * v1.y + a.z * v1.z + a.w * v1.w;
        acc[2] += a.x * v2.x + a.y * v2.y + a.z * v2.z + a.w * v2.w;
        acc[3] += a.x * v3.x + a.y * v3.y + a.z * v3.z + a.w * v3.w;
    }

#pragma unroll
    for (int j = 0; j < 4; ++j)
        out[(size_t)(c0 + j) * NPIX + h * W + w0 + w2] = acc[j];
}

// ---------------------------------------------------------------------------
// Workspace: 6M floats = 24 MB used, non-overlapping:
//   qT [0,1M)  k [1M,2M)  v [2M,3M)  Sd [3M,5M)  Vs [5M,6M)
// ---------------------------------------------------------------------------
extern "C" void kernel_launch(void* const* d_in, const int* in_sizes, int n_in,
                              void* d_out, int out_size, void* d_ws, size_t ws_size,
                              hipStream_t stream)
{
    const float* x  = (const float*)d_in[0];
    const float* Wq = (const float*)d_in[1];
    const float* bq = (const float*)d_in[2];
    const float* Wk = (const float*)d_in[3];
    const float* bk = (const float*)d_in[4];
    const float* Wv = (const float*)d_in[5];
    const float* bv = (const float*)d_in[6];
    float* out = (float*)d_out;

    float* ws = (float*)d_ws;
    const size_t NQ = (size_t)C * NPIX;       // 1M floats
    const size_t NS = (size_t)H * W * W;      // 2M floats

    float* qT   = ws;
    float* k    = ws + NQ;
    float* v    = ws + 2 * NQ;
    float* Sd   = ws + 3 * NQ;
    float* Vsum = ws + 3 * NQ + NS;

    k_conv<<<dim3(NPIX / 64, 4), 256, 0, stream>>>(x, Wq, bq, Wk, bk, Wv, bv, qT, k, v);
    k_mid<<<dim3(1536), 256, 0, stream>>>(qT, k, v, Sd, Vsum);
    k_fused<<<dim3(H, 2), 1024, 0, stream>>>(Sd, Vsum, out);
}